// Round 17
// baseline (6871.906 us; speedup 1.0000x reference)
//
#include <hip/hip_runtime.h>

typedef unsigned short u16;
typedef unsigned long long u64;
typedef __attribute__((ext_vector_type(8))) short bf16x8;
typedef __attribute__((ext_vector_type(4))) float f32x4;
typedef __attribute__((ext_vector_type(4))) u16 u16x4;

// B=128, T=1024, I=512, H=1024
// ws layout (bytes):
//   xw   @ 0          : packed gates [t][jb(64)][b(128)][3][16] bf16 = 805,306,368
//   xbf  @ 805306368  : [131072][512]  bf16 = 134,217,728
//   wt   @ 939524096  : [3072][512]    bf16 (4 MB reserved)
//   wcat @ 943718400  : [5120][1024]   bf16 = 10,485,760 (U_i|U_f|U_g|P_i|P_f cols as rows)
//   cb   @ 954204160  : 2 x [128][1024] bf16 ping-pong (524,288)
//   sp   @ 954728448  : [128][1024] f32 (c_prev at output step)
//   sn   @ 955252736  : [128][1024] f32 (c_new  at output step)
//   bar  @ 955777024  : 4096 B barrier counters (4 independent rb groups, 1KB each)

__device__ __forceinline__ float bf2f(u16 u) { return __uint_as_float(((unsigned)u) << 16); }
__device__ __forceinline__ u16 f2bf(float f) {
  unsigned u = __float_as_uint(f);
  u = (u + 0x7FFFu + ((u >> 16) & 1u)) >> 16;  // RNE
  return (u16)u;
}
__device__ __forceinline__ float sigm_(float x) { return 1.0f / (1.0f + __expf(-x)); }
__device__ __forceinline__ float tanh_(float x) {
  float e = __expf(2.0f * fabsf(x));
  float r = 1.0f - 2.0f / (e + 1.0f);
  return copysignf(r, x);
}
__device__ __forceinline__ void g2l16(const void* g, void* l) {
  __builtin_amdgcn_global_load_lds(
      (const __attribute__((address_space(1))) void*)g,
      (__attribute__((address_space(3))) void*)l, 16, 0, 0);
}

// ---------------- f32 -> bf16 elementwise convert ----------------
__global__ __launch_bounds__(256) void k_cvt(const float* __restrict__ in,
                                             u16* __restrict__ out, int n) {
  int i = (blockIdx.x * 256 + threadIdx.x) * 4;
  if (i >= n) return;
  const float4 v = *(const float4*)(in + i);
  u16x4 o;
  o.x = f2bf(v.x); o.y = f2bf(v.y); o.z = f2bf(v.z); o.w = f2bf(v.w);
  *(u16x4*)(out + i) = o;
}

// ------------- transpose + convert: out[j][k] = (bf16)src[k][j0+j] -------------
__global__ __launch_bounds__(256) void k_tr(const float* __restrict__ src, int ld,
                                            u16* __restrict__ out, int K) {
  __shared__ float tle[64][65];
  int j0 = blockIdx.x * 64, k0 = blockIdx.y * 64;
  int jc = threadIdx.x & 63, kq = threadIdx.x >> 6;
  #pragma unroll
  for (int p = 0; p < 16; ++p) {
    int kr = kq * 16 + p;
    tle[jc][kr] = src[(size_t)(k0 + kr) * ld + j0 + jc];
  }
  __syncthreads();
  #pragma unroll
  for (int p = 0; p < 16; ++p) {
    int jr = kq * 16 + p;
    out[(size_t)(j0 + jr) * K + k0 + jc] = f2bf(tle[jr][jc]);
  }
}

// ---------------- xW GEMM: A[M][512] @ Bt[N][512]^T + bias, PACKED output ----
// 256x128 tile (BM=256: 2x MFMA per staging byte vs the 128^2 R16 version);
// XCD-chunked block remap: the 24 n-blocks sharing one A-panel all land on the
// same XCD's L2 (bid%8 heuristic, bijective 8 x 64 x 24 = 12288 = grid).
// Packing epilogue formula identical to R16 (m-tile of 256 stays in one b).
// writes xw[t][jbp][b][g][16] (elem = ((t*64+jbp)*128 + b)*48 + g*16 + col)
__global__ __launch_bounds__(256) void k_gemm(const u16* __restrict__ A,
                                              const u16* __restrict__ Bt,
                                              const float* __restrict__ bias,
                                              u16* __restrict__ xw) {
  __shared__ u16 lds[24576];  // lA [256][64] (16384) | lB [128][64] (8192)
  const int Kd = 512;
  // XCD-chunked remap of the 12288 blocks (24 x, 512 y)
  int bid = blockIdx.x + blockIdx.y * 24;
  int xcd = bid & 7, g = bid >> 3;          // g in [0, 1536)
  int mt = xcd * 64 + g / 24, nt = g % 24;  // 512 m-tiles, 24 n-tiles
  int n0 = nt * 128, m0 = mt * 256;
  int tid = threadIdx.x, lane = tid & 63, wave = tid >> 6;
  int wm = (wave >> 1) * 128, wn = (wave & 1) * 64;
  int l15 = lane & 15, lk8 = (lane >> 4) * 8;
  f32x4 acc[8][4];
  #pragma unroll
  for (int i = 0; i < 8; ++i)
    #pragma unroll
    for (int j = 0; j < 4; ++j) {
      acc[i][j][0] = 0.f; acc[i][j][1] = 0.f; acc[i][j][2] = 0.f; acc[i][j][3] = 0.f;
    }
  for (int k0 = 0; k0 < Kd; k0 += 64) {
    #pragma unroll
    for (int p = 0; p < 12; ++p) {
      int c = p * 256 + tid;                // 3072 16B chunks: 2048 A + 1024 B
      int ldsbase = (c - lane) * 16;
      int colb = (c & 7) * 16;
      const char* gp;
      if (c < 2048) gp = (const char*)A  + ((size_t)(m0 + (c >> 3)) * Kd + k0) * 2 + colb;
      else          gp = (const char*)Bt + ((size_t)(n0 + ((c - 2048) >> 3)) * Kd + k0) * 2 + colb;
      g2l16(gp, (char*)lds + ldsbase);
    }
    __syncthreads();
    #pragma unroll
    for (int kk = 0; kk < 2; ++kk) {
      bf16x8 af[8], bfr[4];
      #pragma unroll
      for (int mf = 0; mf < 8; ++mf)
        af[mf] = *(const bf16x8*)&lds[(wm + mf * 16 + l15) * 64 + kk * 32 + lk8];
      #pragma unroll
      for (int nf = 0; nf < 4; ++nf)
        bfr[nf] = *(const bf16x8*)&lds[16384 + (wn + nf * 16 + l15) * 64 + kk * 32 + lk8];
      #pragma unroll
      for (int mf = 0; mf < 8; ++mf)
        #pragma unroll
        for (int nf = 0; nf < 4; ++nf)
          acc[mf][nf] = __builtin_amdgcn_mfma_f32_16x16x32_bf16(af[mf], bfr[nf], acc[mf][nf], 0, 0, 0);
    }
    __syncthreads();
  }
  int rbase = (lane >> 4) * 4;
  #pragma unroll
  for (int mf = 0; mf < 8; ++mf)
    #pragma unroll
    for (int nf = 0; nf < 4; ++nf) {
      int n = n0 + wn + nf * 16 + l15;
      float bv = bias[n];
      int gg = n >> 10, j = n & 1023;
      int jbp = j >> 4, col = j & 15;
      #pragma unroll
      for (int r = 0; r < 4; ++r) {
        int m = m0 + wm + mf * 16 + rbase + r;
        int b = m >> 10, t = m & 1023;
        xw[(((size_t)t * 64 + jbp) * 128 + b) * 48 + gg * 16 + col] =
            f2bf(acc[mf][nf][r] + bv);
      }
    }
}

// ---- per-rb fence-free barrier (measured optimum): 2 sub-groups of 32 + master ----
// Barrier-shape ranking measured on MI355X (us/step total): 2x32+master 5.40 <
// 8x8+master 5.96 < 1x64 flat ~7.4 << per-lane flag spin 17.3 (R10: coherent
// vector-load spins are a 10x HBM bomb). tid0-only scalar poll.
__device__ __forceinline__ void gbar_rb(unsigned* bar, unsigned phase, int jb, int rb) {
  __syncthreads();  // drains vmcnt: agent c-stores complete at LLC
  if (threadIdx.x == 0) {
    unsigned* barg = bar + rb * 256;            // 1KB per rb group
    unsigned* gc = barg + (jb >> 5) * 32;       // 2 sub-counters, 128B apart
    unsigned* master = barg + 128;
    unsigned v = __hip_atomic_fetch_add(gc, 1u, __ATOMIC_RELAXED, __HIP_MEMORY_SCOPE_AGENT) + 1;
    if (v == 32u * phase)
      __hip_atomic_fetch_add(master, 1u, __ATOMIC_RELAXED, __HIP_MEMORY_SCOPE_AGENT);
    while (__hip_atomic_load(master, __ATOMIC_RELAXED, __HIP_MEMORY_SCOPE_AGENT) < 2u * phase)
      __builtin_amdgcn_s_sleep(1);
  }
  __syncthreads();
}

// ---------------- persistent recurrence kernel: all 1024 steps ----------------
// R12/R16 verbatim -- the measured best (5.40us/step). Structure: 256 blocks
// (64 jb x 4 rb), 320 thr = 5 waves, wave g owns gate g over full K=1024
// (B-frags register-resident all run). A (c bf16) re-staged per step via
// coherent u64 loads -> XOR-swizzled ds_write. c state in registers; c
// exchange via relaxed agent atomics (LLC point of coherence, no fences).
__global__ __launch_bounds__(320, 1) void k_persist(
    u16* __restrict__ cb, const u16* __restrict__ wcat, const u16* __restrict__ xw,
    const int* __restrict__ lens, float* __restrict__ sp, float* __restrict__ sn,
    unsigned* __restrict__ bar) {
  __shared__ __align__(16) char smem[98304];  // A [32][2048B] 65536 | sgl 5*16*36*4 | pad
  char* Ab = smem;
  float* sgl = (float*)(smem + 65536);        // [g][jj(16)][row 32 pad->36]

  const int bid = blockIdx.x;
  const int jb = bid & 63, rb = bid >> 6;
  const int tid = threadIdx.x;
  const int lane = tid & 63, wave = tid >> 6; // wave = gate index g (0..4)
  const int l15 = lane & 15, lhi = lane >> 4;
  const int swz = (l15 & 7) << 4;

  // ---- B frags once for the whole run (proven layout) ----
  const u16* brow = wcat + ((size_t)(wave * 1024 + jb * 16 + l15)) * 1024 + lhi * 8;
  bf16x8 breg[32];
  #pragma unroll
  for (int kf = 0; kf < 32; ++kf)
    breg[kf] = *(const bf16x8*)(brow + kf * 32);

  // ---- epilogue mapping: 2 outputs per thread, tid<256 ----
  const int erow = tid >> 3, ejj = (tid & 7) * 2;
  const int eb = rb * 32 + erow;
  const int ej0 = jb * 16 + ejj;
  const int mylen = (tid < 256) ? lens[eb] : 0;
  float c0 = 0.f, c1 = 0.f;

  #pragma unroll 1
  for (int t = 0; t < 1024; ++t) {
    const u64* asrc = (const u64*)((const char*)cb + (size_t)(t & 1) * 262144 +
                                   (size_t)rb * 65536);
    u16* cbout = cb + (size_t)((t + 1) & 1) * 131072;

    // this step's packed xW gate words: one coalesced 3KB chunk per block
    unsigned xg0 = 0, xg1 = 0, xg2 = 0;
    if (tid < 256) {
      const u16* xr = xw + (((size_t)t * 64 + jb) * 128 + eb) * 48 + ejj;
      xg0 = *(const unsigned*)(xr);
      xg1 = *(const unsigned*)(xr + 16);
      xg2 = *(const unsigned*)(xr + 32);
    }

    // ---- stage A: 8192 u64 chunks via coherent loads -> swizzled ds_write ----
    u64 av[26];
    #pragma unroll
    for (int i = 0; i < 26; ++i) {
      int c = i * 320 + tid;
      if (c < 8192)
        av[i] = __hip_atomic_load(asrc + c, __ATOMIC_RELAXED, __HIP_MEMORY_SCOPE_AGENT);
    }
    #pragma unroll
    for (int i = 0; i < 26; ++i) {
      int c = i * 320 + tid;
      if (c < 8192) {
        int row = c >> 8, col8 = c & 255;
        *(u64*)(Ab + row * 2048 + ((col8 * 8) ^ ((row & 7) << 4))) = av[i];
      }
    }
    __syncthreads();  // A staged

    // ---- 64 MFMAs, 4 independent 16-deep chains ----
    f32x4 acc0 = {0.f, 0.f, 0.f, 0.f}, acc1 = {0.f, 0.f, 0.f, 0.f};
    f32x4 acc2 = {0.f, 0.f, 0.f, 0.f}, acc3 = {0.f, 0.f, 0.f, 0.f};
    #pragma unroll
    for (int kf = 0; kf < 32; kf += 2) {
      int koffA = (kf * 64 + lhi * 16) ^ swz;
      int koffB = ((kf + 1) * 64 + lhi * 16) ^ swz;
      bf16x8 a0 = *(const bf16x8*)(Ab + l15 * 2048 + koffA);
      bf16x8 a1 = *(const bf16x8*)(Ab + (16 + l15) * 2048 + koffA);
      bf16x8 b0 = *(const bf16x8*)(Ab + l15 * 2048 + koffB);
      bf16x8 b1 = *(const bf16x8*)(Ab + (16 + l15) * 2048 + koffB);
      acc0 = __builtin_amdgcn_mfma_f32_16x16x32_bf16(a0, breg[kf], acc0, 0, 0, 0);
      acc1 = __builtin_amdgcn_mfma_f32_16x16x32_bf16(a1, breg[kf], acc1, 0, 0, 0);
      acc2 = __builtin_amdgcn_mfma_f32_16x16x32_bf16(b0, breg[kf + 1], acc2, 0, 0, 0);
      acc3 = __builtin_amdgcn_mfma_f32_16x16x32_bf16(b1, breg[kf + 1], acc3, 0, 0, 0);
    }
    acc0[0] += acc2[0]; acc0[1] += acc2[1]; acc0[2] += acc2[2]; acc0[3] += acc2[3];
    acc1[0] += acc3[0]; acc1[1] += acc3[1]; acc1[2] += acc3[2]; acc1[3] += acc3[3];

    // ---- publish gate tiles (proven layout) ----
    *(f32x4*)&sgl[(wave * 16 + l15) * 36 + lhi * 4] = acc0;
    *(f32x4*)&sgl[(wave * 16 + l15) * 36 + 16 + lhi * 4] = acc1;
    __syncthreads();

    // ---- fused gate epilogue (proven math), agent-scope c store ----
    if (tid < 256) {
      float ci[2] = {c0, c1};
      float cn2[2];
      u16 nb2[2];
      unsigned xg[3] = {xg0, xg1, xg2};
      #pragma unroll
      for (int e = 0; e < 2; ++e) {
        int col = ejj + e;
        float gi = sgl[(0 * 16 + col) * 36 + erow] + bf2f((u16)(xg[0] >> (e * 16)));
        float gf = sgl[(1 * 16 + col) * 36 + erow] + bf2f((u16)(xg[1] >> (e * 16)));
        float gg = sgl[(2 * 16 + col) * 36 + erow] + bf2f((u16)(xg[2] >> (e * 16)));
        float pi = sgl[(3 * 16 + col) * 36 + erow];
        float pf = sgl[(4 * 16 + col) * 36 + erow];
        float it = sigm_(gi + tanh_(pi));
        float ft = sigm_(gf + tanh_(pf));
        float gt = tanh_(gg);
        float cn = ft * ci[e] + it * gt;
        cn2[e] = cn;
        nb2[e] = f2bf(cn);
      }
      c0 = cn2[0]; c1 = cn2[1];
      __hip_atomic_store((unsigned*)(cbout + (size_t)eb * 1024 + ej0),
                         (unsigned)nb2[0] | ((unsigned)nb2[1] << 16),
                         __ATOMIC_RELAXED, __HIP_MEMORY_SCOPE_AGENT);
      if (t == mylen - 1) {
        *(float2*)(sp + (size_t)eb * 1024 + ej0) = make_float2(ci[0], ci[1]);
        *(float2*)(sn + (size_t)eb * 1024 + ej0) = make_float2(cn2[0], cn2[1]);
      }
    }

    gbar_rb(bar, (unsigned)(t + 1), jb, rb);
  }
}

// ---------------- output pass: o-gate + h at t = lens[b]-1 ----------------
__global__ __launch_bounds__(256) void k_final(
    const int* __restrict__ lens, const float* __restrict__ x,
    const float* __restrict__ W, const float* __restrict__ U,
    const float* __restrict__ Po, const float* __restrict__ bias,
    const float* __restrict__ sp, const float* __restrict__ sn,
    float* __restrict__ out) {
  __shared__ float scp[1024], scn[1024], sx[512];
  int b = blockIdx.x, tid = threadIdx.x;
  int t = lens[b] - 1;
  for (int k = tid; k < 1024; k += 256) {
    scp[k] = sp[b * 1024 + k];
    scn[k] = sn[b * 1024 + k];
  }
  for (int k = tid; k < 512; k += 256)
    sx[k] = x[(size_t)(b * 1024 + t) * 512 + k];
  __syncthreads();
  for (int j = tid; j < 1024; j += 256) {
    float au = 0.f, ap = 0.f, ax = 0.f;
    for (int k = 0; k < 1024; ++k) {
      au = fmaf(scp[k], U[(size_t)k * 4096 + 3072 + j], au);
      ap = fmaf(scn[k], Po[(size_t)k * 1024 + j], ap);
    }
    for (int k = 0; k < 512; ++k)
      ax = fmaf(sx[k], W[(size_t)k * 4096 + 3072 + j], ax);
    float go = ax + bias[3072 + j] + au;
    float o = sigm_(go + tanh_(ap));
    out[b * 1024 + j] = o * tanh_(scn[j]);
  }
}

extern "C" void kernel_launch(void* const* d_in, const int* in_sizes, int n_in,
                              void* d_out, int out_size, void* d_ws, size_t ws_size,
                              hipStream_t stream) {
  const float* x    = (const float*)d_in[0];
  const int*   lens = (const int*)d_in[1];
  const float* W    = (const float*)d_in[2];
  const float* U    = (const float*)d_in[3];
  const float* P    = (const float*)d_in[4];
  const float* Po   = (const float*)d_in[5];
  const float* bias = (const float*)d_in[6];
  float* out = (float*)d_out;
  char* ws = (char*)d_ws;

  u16*      xw   = (u16*)(ws);
  u16*      xbf  = (u16*)(ws + 805306368LL);
  u16*      wt   = (u16*)(ws + 939524096LL);
  u16*      wcat = (u16*)(ws + 943718400LL);
  u16*      cbp  = (u16*)(ws + 954204160LL);
  float*    sp   = (float*)(ws + 954728448LL);
  float*    sn   = (float*)(ws + 955252736LL);
  unsigned* bar  = (unsigned*)(ws + 955777024LL);

  // zero c[0] shadow + barrier counters (re-done every call/replay)
  hipMemsetAsync(cbp, 0, 262144, stream);
  hipMemsetAsync(bar, 0, 4096, stream);

  k_cvt<<<65536, 256, 0, stream>>>(x, xbf, 67108864);
  k_tr<<<dim3(48, 8), 256, 0, stream>>>(W, 4096, wt, 512);
  k_tr<<<dim3(48, 16), 256, 0, stream>>>(U, 4096, wcat, 1024);
  k_tr<<<dim3(32, 16), 256, 0, stream>>>(P, 2048, wcat + (size_t)3072 * 1024, 1024);
  k_gemm<<<dim3(24, 512), 256, 0, stream>>>(xbf, wt, bias, xw);

  void* ka[] = {(void*)&cbp, (void*)&wcat, (void*)&xw, (void*)&lens,
                (void*)&sp, (void*)&sn, (void*)&bar};
  hipLaunchCooperativeKernel((const void*)k_persist, dim3(256), dim3(320), ka, 0, stream);

  k_final<<<128, 256, 0, stream>>>(lens, x, W, U, Po, bias, sp, sn, out);
}

// Round 18
// 6696.778 us; speedup vs baseline: 1.0262x; 1.0262x over previous
//
#include <hip/hip_runtime.h>

typedef unsigned short u16;
typedef unsigned long long u64;
typedef __attribute__((ext_vector_type(8))) short bf16x8;
typedef __attribute__((ext_vector_type(4))) float f32x4;
typedef __attribute__((ext_vector_type(4))) u16 u16x4;

// B=128, T=1024, I=512, H=1024
// ws layout (bytes):
//   xw   @ 0          : packed gates [t][jb(64)][b(128)][3][16] bf16 = 805,306,368
//   xbf  @ 805306368  : [131072][512]  bf16 = 134,217,728
//   wt   @ 939524096  : [3072][512]    bf16 (4 MB reserved)
//   wcat @ 943718400  : [5120][1024]   bf16 = 10,485,760 (U_i|U_f|U_g|P_i|P_f cols as rows)
//   cb   @ 954204160  : 2 x [128][1024] bf16 ping-pong (524,288)
//   sp   @ 954728448  : [128][1024] f32 (c_prev at output step)
//   sn   @ 955252736  : [128][1024] f32 (c_new  at output step)
//   bar  @ 955777024  : 4096 B barrier counters (4 independent rb groups, 1KB each)
//
// Session ranking notes (measured):
//  - k_gemm tile: 128x128/24KB-LDS (this) > 256x128/48KB-LDS + XCD remap (R17: +110us)
//  - barrier: 2x32+master 5.40us/step < 8x8+master 5.96 < 1x64 flat 7.4 << lane-spin 17.3
//  - c exchange: relaxed agent atomics (no fences) -- threadfence gbar costs 13us/step (R7)
//  - k_persist resource envelope: 320thr/128VGPR/<=96KB LDS; outside it coop launch
//    silently no-ops (R3/R4/R13 all-zeros signature)

__device__ __forceinline__ float bf2f(u16 u) { return __uint_as_float(((unsigned)u) << 16); }
__device__ __forceinline__ u16 f2bf(float f) {
  unsigned u = __float_as_uint(f);
  u = (u + 0x7FFFu + ((u >> 16) & 1u)) >> 16;  // RNE
  return (u16)u;
}
__device__ __forceinline__ float sigm_(float x) { return 1.0f / (1.0f + __expf(-x)); }
__device__ __forceinline__ float tanh_(float x) {
  float e = __expf(2.0f * fabsf(x));
  float r = 1.0f - 2.0f / (e + 1.0f);
  return copysignf(r, x);
}
__device__ __forceinline__ void g2l16(const void* g, void* l) {
  __builtin_amdgcn_global_load_lds(
      (const __attribute__((address_space(1))) void*)g,
      (__attribute__((address_space(3))) void*)l, 16, 0, 0);
}

// ---------------- f32 -> bf16 elementwise convert ----------------
__global__ __launch_bounds__(256) void k_cvt(const float* __restrict__ in,
                                             u16* __restrict__ out, int n) {
  int i = (blockIdx.x * 256 + threadIdx.x) * 4;
  if (i >= n) return;
  const float4 v = *(const float4*)(in + i);
  u16x4 o;
  o.x = f2bf(v.x); o.y = f2bf(v.y); o.z = f2bf(v.z); o.w = f2bf(v.w);
  *(u16x4*)(out + i) = o;
}

// ------------- transpose + convert: out[j][k] = (bf16)src[k][j0+j] -------------
__global__ __launch_bounds__(256) void k_tr(const float* __restrict__ src, int ld,
                                            u16* __restrict__ out, int K) {
  __shared__ float tle[64][65];
  int j0 = blockIdx.x * 64, k0 = blockIdx.y * 64;
  int jc = threadIdx.x & 63, kq = threadIdx.x >> 6;
  #pragma unroll
  for (int p = 0; p < 16; ++p) {
    int kr = kq * 16 + p;
    tle[jc][kr] = src[(size_t)(k0 + kr) * ld + j0 + jc];
  }
  __syncthreads();
  #pragma unroll
  for (int p = 0; p < 16; ++p) {
    int jr = kq * 16 + p;
    out[(size_t)(j0 + jr) * K + k0 + jc] = f2bf(tle[jr][jc]);
  }
}

// ---------------- xW GEMM: A[M][512] @ Bt[N][512]^T + bias, PACKED output ----
// writes xw[t][jbp][b][g][16] (elem = ((t*64+jbp)*128 + b)*48 + g*16 + col)
__global__ __launch_bounds__(256) void k_gemm(const u16* __restrict__ A,
                                              const u16* __restrict__ Bt,
                                              const float* __restrict__ bias,
                                              u16* __restrict__ xw) {
  __shared__ u16 lds[16384];  // lA [128][64] | lB [128][64]
  const int Kd = 512;
  int n0 = blockIdx.x * 128, m0 = blockIdx.y * 128;
  int tid = threadIdx.x, lane = tid & 63, wave = tid >> 6;
  int wm = (wave >> 1) * 64, wn = (wave & 1) * 64;
  int l15 = lane & 15, lk8 = (lane >> 4) * 8;
  f32x4 acc[4][4];
  #pragma unroll
  for (int i = 0; i < 4; ++i)
    #pragma unroll
    for (int j = 0; j < 4; ++j) {
      acc[i][j][0] = 0.f; acc[i][j][1] = 0.f; acc[i][j][2] = 0.f; acc[i][j][3] = 0.f;
    }
  for (int k0 = 0; k0 < Kd; k0 += 64) {
    #pragma unroll
    for (int p = 0; p < 8; ++p) {
      int c = p * 256 + tid;
      int ldsbase = (c - lane) * 16;
      int row = (c & 1023) >> 3, colb = (c & 7) * 16;
      const char* g;
      if (c < 1024) g = (const char*)A  + ((size_t)(m0 + row) * Kd + k0) * 2 + colb;
      else          g = (const char*)Bt + ((size_t)(n0 + row) * Kd + k0) * 2 + colb;
      g2l16(g, (char*)lds + ldsbase);
    }
    __syncthreads();
    #pragma unroll
    for (int kk = 0; kk < 2; ++kk) {
      bf16x8 af[4], bfr[4];
      #pragma unroll
      for (int mf = 0; mf < 4; ++mf)
        af[mf] = *(const bf16x8*)&lds[(wm + mf * 16 + l15) * 64 + kk * 32 + lk8];
      #pragma unroll
      for (int nf = 0; nf < 4; ++nf)
        bfr[nf] = *(const bf16x8*)&lds[8192 + (wn + nf * 16 + l15) * 64 + kk * 32 + lk8];
      #pragma unroll
      for (int mf = 0; mf < 4; ++mf)
        #pragma unroll
        for (int nf = 0; nf < 4; ++nf)
          acc[mf][nf] = __builtin_amdgcn_mfma_f32_16x16x32_bf16(af[mf], bfr[nf], acc[mf][nf], 0, 0, 0);
    }
    __syncthreads();
  }
  int rbase = (lane >> 4) * 4;
  #pragma unroll
  for (int mf = 0; mf < 4; ++mf)
    #pragma unroll
    for (int nf = 0; nf < 4; ++nf) {
      int n = n0 + wn + nf * 16 + l15;
      float bv = bias[n];
      int g = n >> 10, j = n & 1023;
      int jbp = j >> 4, col = j & 15;
      #pragma unroll
      for (int r = 0; r < 4; ++r) {
        int m = m0 + wm + mf * 16 + rbase + r;
        int b = m >> 10, t = m & 1023;
        xw[(((size_t)t * 64 + jbp) * 128 + b) * 48 + g * 16 + col] =
            f2bf(acc[mf][nf][r] + bv);
      }
    }
}

// ---- per-rb fence-free barrier (measured optimum): 2 sub-groups of 32 + master ----
__device__ __forceinline__ void gbar_rb(unsigned* bar, unsigned phase, int jb, int rb) {
  __syncthreads();  // drains vmcnt: agent c-stores complete at LLC
  if (threadIdx.x == 0) {
    unsigned* barg = bar + rb * 256;            // 1KB per rb group
    unsigned* gc = barg + (jb >> 5) * 32;       // 2 sub-counters, 128B apart
    unsigned* master = barg + 128;
    unsigned v = __hip_atomic_fetch_add(gc, 1u, __ATOMIC_RELAXED, __HIP_MEMORY_SCOPE_AGENT) + 1;
    if (v == 32u * phase)
      __hip_atomic_fetch_add(master, 1u, __ATOMIC_RELAXED, __HIP_MEMORY_SCOPE_AGENT);
    while (__hip_atomic_load(master, __ATOMIC_RELAXED, __HIP_MEMORY_SCOPE_AGENT) < 2u * phase)
      __builtin_amdgcn_s_sleep(1);
  }
  __syncthreads();
}

// ---------------- persistent recurrence kernel: all 1024 steps ----------------
// Measured best (5.40us/step). 256 blocks (64 jb x 4 rb), 320 thr = 5 waves,
// wave g owns gate g over full K=1024 (B-frags register-resident all run).
// A (c bf16) re-staged per step via coherent u64 loads -> XOR-swizzled
// ds_write. c state in registers; c exchange via relaxed agent atomics.
__global__ __launch_bounds__(320, 1) void k_persist(
    u16* __restrict__ cb, const u16* __restrict__ wcat, const u16* __restrict__ xw,
    const int* __restrict__ lens, float* __restrict__ sp, float* __restrict__ sn,
    unsigned* __restrict__ bar) {
  __shared__ __align__(16) char smem[98304];  // A [32][2048B] 65536 | sgl 5*16*36*4 | pad
  char* Ab = smem;
  float* sgl = (float*)(smem + 65536);        // [g][jj(16)][row 32 pad->36]

  const int bid = blockIdx.x;
  const int jb = bid & 63, rb = bid >> 6;
  const int tid = threadIdx.x;
  const int lane = tid & 63, wave = tid >> 6; // wave = gate index g (0..4)
  const int l15 = lane & 15, lhi = lane >> 4;
  const int swz = (l15 & 7) << 4;

  // ---- B frags once for the whole run (proven layout) ----
  const u16* brow = wcat + ((size_t)(wave * 1024 + jb * 16 + l15)) * 1024 + lhi * 8;
  bf16x8 breg[32];
  #pragma unroll
  for (int kf = 0; kf < 32; ++kf)
    breg[kf] = *(const bf16x8*)(brow + kf * 32);

  // ---- epilogue mapping: 2 outputs per thread, tid<256 ----
  const int erow = tid >> 3, ejj = (tid & 7) * 2;
  const int eb = rb * 32 + erow;
  const int ej0 = jb * 16 + ejj;
  const int mylen = (tid < 256) ? lens[eb] : 0;
  float c0 = 0.f, c1 = 0.f;

  #pragma unroll 1
  for (int t = 0; t < 1024; ++t) {
    const u64* asrc = (const u64*)((const char*)cb + (size_t)(t & 1) * 262144 +
                                   (size_t)rb * 65536);
    u16* cbout = cb + (size_t)((t + 1) & 1) * 131072;

    // this step's packed xW gate words: one coalesced 3KB chunk per block
    unsigned xg0 = 0, xg1 = 0, xg2 = 0;
    if (tid < 256) {
      const u16* xr = xw + (((size_t)t * 64 + jb) * 128 + eb) * 48 + ejj;
      xg0 = *(const unsigned*)(xr);
      xg1 = *(const unsigned*)(xr + 16);
      xg2 = *(const unsigned*)(xr + 32);
    }

    // ---- stage A: 8192 u64 chunks via coherent loads -> swizzled ds_write ----
    u64 av[26];
    #pragma unroll
    for (int i = 0; i < 26; ++i) {
      int c = i * 320 + tid;
      if (c < 8192)
        av[i] = __hip_atomic_load(asrc + c, __ATOMIC_RELAXED, __HIP_MEMORY_SCOPE_AGENT);
    }
    #pragma unroll
    for (int i = 0; i < 26; ++i) {
      int c = i * 320 + tid;
      if (c < 8192) {
        int row = c >> 8, col8 = c & 255;
        *(u64*)(Ab + row * 2048 + ((col8 * 8) ^ ((row & 7) << 4))) = av[i];
      }
    }
    __syncthreads();  // A staged

    // ---- 64 MFMAs, 4 independent 16-deep chains ----
    f32x4 acc0 = {0.f, 0.f, 0.f, 0.f}, acc1 = {0.f, 0.f, 0.f, 0.f};
    f32x4 acc2 = {0.f, 0.f, 0.f, 0.f}, acc3 = {0.f, 0.f, 0.f, 0.f};
    #pragma unroll
    for (int kf = 0; kf < 32; kf += 2) {
      int koffA = (kf * 64 + lhi * 16) ^ swz;
      int koffB = ((kf + 1) * 64 + lhi * 16) ^ swz;
      bf16x8 a0 = *(const bf16x8*)(Ab + l15 * 2048 + koffA);
      bf16x8 a1 = *(const bf16x8*)(Ab + (16 + l15) * 2048 + koffA);
      bf16x8 b0 = *(const bf16x8*)(Ab + l15 * 2048 + koffB);
      bf16x8 b1 = *(const bf16x8*)(Ab + (16 + l15) * 2048 + koffB);
      acc0 = __builtin_amdgcn_mfma_f32_16x16x32_bf16(a0, breg[kf], acc0, 0, 0, 0);
      acc1 = __builtin_amdgcn_mfma_f32_16x16x32_bf16(a1, breg[kf], acc1, 0, 0, 0);
      acc2 = __builtin_amdgcn_mfma_f32_16x16x32_bf16(b0, breg[kf + 1], acc2, 0, 0, 0);
      acc3 = __builtin_amdgcn_mfma_f32_16x16x32_bf16(b1, breg[kf + 1], acc3, 0, 0, 0);
    }
    acc0[0] += acc2[0]; acc0[1] += acc2[1]; acc0[2] += acc2[2]; acc0[3] += acc2[3];
    acc1[0] += acc3[0]; acc1[1] += acc3[1]; acc1[2] += acc3[2]; acc1[3] += acc3[3];

    // ---- publish gate tiles (proven layout) ----
    *(f32x4*)&sgl[(wave * 16 + l15) * 36 + lhi * 4] = acc0;
    *(f32x4*)&sgl[(wave * 16 + l15) * 36 + 16 + lhi * 4] = acc1;
    __syncthreads();

    // ---- fused gate epilogue (proven math), agent-scope c store ----
    if (tid < 256) {
      float ci[2] = {c0, c1};
      float cn2[2];
      u16 nb2[2];
      unsigned xg[3] = {xg0, xg1, xg2};
      #pragma unroll
      for (int e = 0; e < 2; ++e) {
        int col = ejj + e;
        float gi = sgl[(0 * 16 + col) * 36 + erow] + bf2f((u16)(xg[0] >> (e * 16)));
        float gf = sgl[(1 * 16 + col) * 36 + erow] + bf2f((u16)(xg[1] >> (e * 16)));
        float gg = sgl[(2 * 16 + col) * 36 + erow] + bf2f((u16)(xg[2] >> (e * 16)));
        float pi = sgl[(3 * 16 + col) * 36 + erow];
        float pf = sgl[(4 * 16 + col) * 36 + erow];
        float it = sigm_(gi + tanh_(pi));
        float ft = sigm_(gf + tanh_(pf));
        float gt = tanh_(gg);
        float cn = ft * ci[e] + it * gt;
        cn2[e] = cn;
        nb2[e] = f2bf(cn);
      }
      c0 = cn2[0]; c1 = cn2[1];
      __hip_atomic_store((unsigned*)(cbout + (size_t)eb * 1024 + ej0),
                         (unsigned)nb2[0] | ((unsigned)nb2[1] << 16),
                         __ATOMIC_RELAXED, __HIP_MEMORY_SCOPE_AGENT);
      if (t == mylen - 1) {
        *(float2*)(sp + (size_t)eb * 1024 + ej0) = make_float2(ci[0], ci[1]);
        *(float2*)(sn + (size_t)eb * 1024 + ej0) = make_float2(cn2[0], cn2[1]);
      }
    }

    gbar_rb(bar, (unsigned)(t + 1), jb, rb);
  }
}

// ---------------- output pass: o-gate + h at t = lens[b]-1 ----------------
__global__ __launch_bounds__(256) void k_final(
    const int* __restrict__ lens, const float* __restrict__ x,
    const float* __restrict__ W, const float* __restrict__ U,
    const float* __restrict__ Po, const float* __restrict__ bias,
    const float* __restrict__ sp, const float* __restrict__ sn,
    float* __restrict__ out) {
  __shared__ float scp[1024], scn[1024], sx[512];
  int b = blockIdx.x, tid = threadIdx.x;
  int t = lens[b] - 1;
  for (int k = tid; k < 1024; k += 256) {
    scp[k] = sp[b * 1024 + k];
    scn[k] = sn[b * 1024 + k];
  }
  for (int k = tid; k < 512; k += 256)
    sx[k] = x[(size_t)(b * 1024 + t) * 512 + k];
  __syncthreads();
  for (int j = tid; j < 1024; j += 256) {
    float au = 0.f, ap = 0.f, ax = 0.f;
    for (int k = 0; k < 1024; ++k) {
      au = fmaf(scp[k], U[(size_t)k * 4096 + 3072 + j], au);
      ap = fmaf(scn[k], Po[(size_t)k * 1024 + j], ap);
    }
    for (int k = 0; k < 512; ++k)
      ax = fmaf(sx[k], W[(size_t)k * 4096 + 3072 + j], ax);
    float go = ax + bias[3072 + j] + au;
    float o = sigm_(go + tanh_(ap));
    out[b * 1024 + j] = o * tanh_(scn[j]);
  }
}

extern "C" void kernel_launch(void* const* d_in, const int* in_sizes, int n_in,
                              void* d_out, int out_size, void* d_ws, size_t ws_size,
                              hipStream_t stream) {
  const float* x    = (const float*)d_in[0];
  const int*   lens = (const int*)d_in[1];
  const float* W    = (const float*)d_in[2];
  const float* U    = (const float*)d_in[3];
  const float* P    = (const float*)d_in[4];
  const float* Po   = (const float*)d_in[5];
  const float* bias = (const float*)d_in[6];
  float* out = (float*)d_out;
  char* ws = (char*)d_ws;

  u16*      xw   = (u16*)(ws);
  u16*      xbf  = (u16*)(ws + 805306368LL);
  u16*      wt   = (u16*)(ws + 939524096LL);
  u16*      wcat = (u16*)(ws + 943718400LL);
  u16*      cbp  = (u16*)(ws + 954204160LL);
  float*    sp   = (float*)(ws + 954728448LL);
  float*    sn   = (float*)(ws + 955252736LL);
  unsigned* bar  = (unsigned*)(ws + 955777024LL);

  // zero c[0] shadow + barrier counters (re-done every call/replay)
  hipMemsetAsync(cbp, 0, 262144, stream);
  hipMemsetAsync(bar, 0, 4096, stream);

  k_cvt<<<65536, 256, 0, stream>>>(x, xbf, 67108864);
  k_tr<<<dim3(48, 8), 256, 0, stream>>>(W, 4096, wt, 512);
  k_tr<<<dim3(48, 16), 256, 0, stream>>>(U, 4096, wcat, 1024);
  k_tr<<<dim3(32, 16), 256, 0, stream>>>(P, 2048, wcat + (size_t)3072 * 1024, 1024);
  k_gemm<<<dim3(24, 1024), 256, 0, stream>>>(xbf, wt, bias, xw);

  void* ka[] = {(void*)&cbp, (void*)&wcat, (void*)&xw, (void*)&lens,
                (void*)&sp, (void*)&sn, (void*)&bar};
  hipLaunchCooperativeKernel((const void*)k_persist, dim3(256), dim3(320), ka, 0, stream);

  k_final<<<128, 256, 0, stream>>>(lens, x, W, U, Po, bias, sp, sn, out);
}